// Round 1
// baseline (246.725 us; speedup 1.0000x reference)
//
#include <hip/hip_runtime.h>
#include <math.h>

// Problem constants (match reference)
constexpr int B = 256;
constexpr int T = 16384;
constexpr int K = 3;

// Speculative chunking: emit 256 steps after 512-step f64 warm-up (proven R5/R6).
constexpr int CHUNK = 256;
constexpr int WARM  = 512;

// Conv tiling: 64 chains x 128 timesteps per block, 4 waves x 32 t each.
constexpr int CBT = 128;
constexpr int CWT = 32;

// w64 panel layout [T/16][4 bg][24 q][64 lane] x 16B:
// chunk q of lane i = doubles (2q, 2q+1) of chain (bg*64+i)'s within-panel
// stream ordered (t_local 0..15) x (ch 0..2). Scan loads are then perfectly
// lane-coalesced; the LDS image after global_load_lds is the identical
// linear 24KB slab (uniform base + lane*16 == +lane double2).

// ---------------------------------------------------------------------------
// Conv: causal k=8/16/32 in f64 (same tap order / fma / scale as R2-R6).
// Lane = chain, 32-double sliding ring window from LDS-staged x.
// UNCHANGED this round (no counters for it yet; scan was the profiled hotspot).
// ---------------------------------------------------------------------------
__global__ __launch_bounds__(256, 2) void conv_kernel(
    const float* __restrict__ x,
    const float* __restrict__ w0f,
    const float* __restrict__ w1f,
    const float* __restrict__ w2f,
    float*  __restrict__ u_out,   // [B][K][T] f32
    double* __restrict__ w64)     // panel layout above
{
    const int blk = blockIdx.x;            // 512 blocks
    const int bgi = blk >> 7;              // 4 b-tiles
    const int t0  = (blk & 127) * CBT;     // 128 t-tiles
    const int b0  = bgi * 64;
    const int tid = threadIdx.x;

    __shared__ float sx[64][164];          // cols t0-32 .. t0+127, +4 pad (41 words: 2-way free)
    for (int k = tid; k < 64 * 40; k += 256) {
        const int r  = k / 40;
        const int c4 = k - r * 40;
        const int g  = t0 - 32 + 4 * c4;
        float4 v = make_float4(0.f, 0.f, 0.f, 0.f);
        if (g >= 0) v = *(const float4*)(x + (size_t)(b0 + r) * T + g);
        *(float4*)&sx[r][4 * c4] = v;
    }
    __syncthreads();

    const int lane    = tid & 63;
    const int w       = tid >> 6;
    const int t_start = t0 + CWT * w;

    double w0d[8], w1d[16], w2d[32];
#pragma unroll
    for (int i = 0; i < 8; ++i)  w0d[i] = (double)w0f[i];
#pragma unroll
    for (int i = 0; i < 16; ++i) w1d[i] = (double)w1f[i];
#pragma unroll
    for (int i = 0; i < 32; ++i) w2d[i] = (double)w2f[i];

    // ring window: win[t & 31] = x[chain][t]
    double win[32];
#pragma unroll
    for (int k = 1; k < 32; ++k) win[k] = (double)sx[lane][CWT * w + k];

    const double s8  = 1.0 / sqrt(8.0);
    const double s32 = 1.0 / sqrt(32.0);

    float fr0[16], fr1[16], fr2[16];
    float* uf = u_out + (size_t)(b0 + lane) * (3 * T);

#pragma unroll
    for (int j = 0; j < CWT; ++j) {
        win[j & 31] = (double)sx[lane][CWT * w + 32 + j];   // push x[t]
        double a0 = 0.0, a1 = 0.0, a2 = 0.0;
#pragma unroll
        for (int i = 0; i < 8; ++i)  a0 = fma(w0d[i], win[(j + 25 + i) & 31], a0);
#pragma unroll
        for (int i = 0; i < 16; ++i) a1 = fma(w1d[i], win[(j + 17 + i) & 31], a1);
#pragma unroll
        for (int i = 0; i < 32; ++i) a2 = fma(w2d[i], win[(j + 1 + i) & 31], a2);
        a0 *= s8; a1 *= 0.25; a2 *= s32;

        const int t = t_start + j;
        // panel store: chunk/halves are compile-time static per (j, ch)
        double* wp = w64 + ((size_t)(t >> 4) * 4 + bgi) * 3072 + (size_t)lane * 2;
        const int D0 = (j & 15) * 3;                        // t&15 == j&15
        wp[((D0    ) >> 1) * 128 + ((D0    ) & 1)] = a0 - 0.05;
        wp[((D0 + 1) >> 1) * 128 + ((D0 + 1) & 1)] = a1 - 0.05;
        wp[((D0 + 2) >> 1) * 128 + ((D0 + 2) & 1)] = a2 - 0.05;

        fr0[j & 15] = (float)a0; fr1[j & 15] = (float)a1; fr2[j & 15] = (float)a2;
        if ((j & 15) == 15) {
            float* d = uf + t_start + (j & ~15);
#pragma unroll
            for (int q = 0; q < 4; ++q) {
                *(float4*)(d + 4 * q)         = ((float4*)fr0)[q];
                *(float4*)(d + T + 4 * q)     = ((float4*)fr1)[q];
                *(float4*)(d + 2 * T + 4 * q) = ((float4*)fr2)[q];
            }
        }
    }
}

// ---------------------------------------------------------------------------
// Scan: speculative chunked LIF-WTA, one (chain, chunk) per lane, 1 wave/CU.
// R7 REWRITE of the buffering only: the register triple-buffer (3x48 f64 =
// 144 VGPRs) did not fit in the 176-VGPR allocation -> the compiler sank the
// prefetch loads to their uses -> ~4.6k cy/phase of raw memory latency
// (93.5 us, VALUBusy 7.5%). Panel groups are now DMA'd global->LDS with
// __builtin_amdgcn_global_load_lds (no VGPR cost, un-sinkable) into a
// 3-slab ring (72 KB), with explicit counted s_waitcnt vmcnt(N) so 2 slabs
// (48 loads) stay in flight across phases. The STEP numeric path, warm/emit
// schedule and store pattern are bit-identical to the proven R5/R6 kernel
// (W values travel panel -> LDS -> ds_read as raw f64 bytes).
// ---------------------------------------------------------------------------
__global__ __launch_bounds__(64, 1) void scan_kernel(
    const double* __restrict__ w64,
    float* __restrict__ s_out)        // [B][K][T] f32
{
    const int c    = blockIdx.x & 63;
    const int bg   = blockIdx.x >> 6;
    const int lane = threadIdx.x;
    const int chain = bg * 64 + lane;

    const int t_emit = c * CHUNK;
    const int t_w    = (t_emit >= WARM) ? (t_emit - WARM) : 0;
    const int warm_g = (t_emit - t_w) >> 4;     // 0, 16, or 32
    const int n_g    = warm_g + (CHUNK >> 4);   // 16, 32, or 48
    const int tw16   = t_w >> 4;

    float* sb = s_out + (size_t)chain * (3 * T);

    // 3 slabs x 24 KB (one 16-step group each) = 72 KB LDS ring.
    __shared__ double2 lbuf[3 * 1536];

    double m0 = -1.0, m1 = -1.0, m2 = -1.0;     // v=0 -> m=-1 exactly

// Counted-vmcnt wait (T4). Safe because vmcnt retires in issue order and
// every N used below is <= the statically-known number of vmem ops issued
// after the slab's 24 DMA loads (48 newer loads + 12 stores per emit phase,
// clamped at the 63 encodable max when the true count is 72).
#define WAITN(N) asm volatile("s_waitcnt vmcnt(" #N ")" ::: "memory")

// DMA one 24 KB group into slab s: 24 instrs, each 64 lanes x 16 B.
// LDS dest = wave-uniform base (+ lane*16 by HW) == linear image of the
// global slab, so per-step ds_read offsets reproduce the register layout.
#define LOADDMA(s, gg) do {                                                   \
    const double2* _src = (const double2*)(w64 +                              \
        ((size_t)(tw16 + (gg)) * 4 + bg) * 3072) + lane;                      \
    _Pragma("unroll")                                                         \
    for (int _q = 0; _q < 24; ++_q)                                           \
        __builtin_amdgcn_global_load_lds(                                     \
            (const __attribute__((address_space(1))) void*)(const void*)      \
                (_src + (size_t)_q * 64),                                     \
            (__attribute__((address_space(3))) void*)(void*)                  \
                (&lbuf[(s) * 1536 + _q * 64]),                                \
            16, 0, 0);                                                        \
} while (0)

#define STEP(W0, W1, W2, O0, O1, O2) do {                               \
    const double M0 = fma(0.95, m0, (W0));                              \
    const double M1 = fma(0.95, m1, (W1));                              \
    const double M2 = fma(0.95, m2, (W2));                              \
    const bool c01 = (M0 >= M1);                                        \
    const bool c02 = (M0 >= M2);                                        \
    const bool c12 = (M1 >= M2);                                        \
    const bool f0  = (M0 >= 0.0);                                       \
    const bool f1  = (M1 >= 0.0);                                       \
    const bool f2  = (M2 >= 0.0);                                       \
    const bool s0 = c01 & c02 & f0;          /* first-index argmax */   \
    const bool s1 = (!c01) & c12 & f1;                                  \
    const bool s2 = (!c02) & (!c12) & f2;                               \
    m0 = s0 ? M0 - 1.0 : M0;                                            \
    m1 = s1 ? M1 - 1.0 : M1;                                            \
    m2 = s2 ? M2 - 1.0 : M2;                                            \
    (O0) = s0 ? 1.0f : 0.0f;                                            \
    (O1) = s1 ? 1.0f : 0.0f;                                            \
    (O2) = s2 ? 1.0f : 0.0f;                                            \
} while (0)

// Per-phase wait-count derivation (issue order: prologue L0,L1,L2; phase p:
// WAIT -> compute -> stores(p) -> L(p+3)). Newer-than-L(p) =
// 24*[p+1<n_g] + 24*[p+2<n_g] + 12*emit(p-1) + 12*emit(p-2):
//   warm steady: 48 | first post-warm: 60 | emit steady: 72 -> clamp 63
//   p = n_g-2: 24+12+12 = 48 | p = n_g-1: 12+12 = 24
#define BODY(s, pp) do {                                                      \
    if ((pp) < n_g) {                                                         \
        if ((pp) == n_g - 1)            WAITN(24);                            \
        else if ((pp) == n_g - 2)       WAITN(48);                            \
        else if ((pp) >= warm_g + 2)    WAITN(63);                            \
        else if ((pp) == warm_g + 1)    WAITN(60);                            \
        else                            WAITN(48);                            \
        const double* _lp = (const double*)(lbuf + (s) * 1536) + 2 * lane;    \
        float sp0[16], sp1[16], sp2[16];                                      \
        _Pragma("unroll")                                                     \
        for (int _j = 0; _j < 16; ++_j) {                                     \
            const int _d0 = 3 * _j;                                           \
            const double _W0 = _lp[((_d0    ) >> 1) * 128 + ((_d0    ) & 1)]; \
            const double _W1 = _lp[((_d0 + 1) >> 1) * 128 + ((_d0 + 1) & 1)]; \
            const double _W2 = _lp[((_d0 + 2) >> 1) * 128 + ((_d0 + 2) & 1)]; \
            STEP(_W0, _W1, _W2, sp0[_j], sp1[_j], sp2[_j]);                   \
        }                                                                     \
        if ((pp) >= warm_g) {                                                 \
            float* _d = sb + t_w + (size_t)(pp) * 16;                         \
            _Pragma("unroll")                                                 \
            for (int _q = 0; _q < 4; ++_q) {                                  \
                *(float4*)(_d + 4*_q)         = ((float4*)sp0)[_q];           \
                *(float4*)(_d + T + 4*_q)     = ((float4*)sp1)[_q];           \
                *(float4*)(_d + 2*T + 4*_q)   = ((float4*)sp2)[_q];           \
            }                                                                 \
        }                                                                     \
        if ((pp) + 3 < n_g) {                                                 \
            /* WAR fence: all ds_reads of slab s must land before DMA       */\
            /* re-targets it (DMA writes LDS at data-return, not in ds      */\
            /* order). Dep-chain has already drained most of lgkm: ~free.   */\
            asm volatile("s_waitcnt lgkmcnt(0)" ::: "memory");                \
            LOADDMA(s, (pp) + 3);                                             \
        }                                                                     \
    }                                                                         \
} while (0)

    LOADDMA(0, 0);
    LOADDMA(1, 1);
    LOADDMA(2, 2);
    for (int p = 0; p < n_g; p += 3) {
        BODY(0, p);
        BODY(1, p + 1);
        BODY(2, p + 2);
    }

#undef BODY
#undef STEP
#undef LOADDMA
#undef WAITN
}

// ---------------------------------------------------------------------------
extern "C" void kernel_launch(void* const* d_in, const int* in_sizes, int n_in,
                              void* d_out, int out_size, void* d_ws, size_t ws_size,
                              hipStream_t stream)
{
    const float* x  = (const float*)d_in[0];
    const float* w0 = (const float*)d_in[1];
    const float* w1 = (const float*)d_in[2];
    const float* w2 = (const float*)d_in[3];
    // d_in[4] = y (unused by the reference outputs)

    float* out   = (float*)d_out;
    float* u_out = out;                        // [B][K][T]
    float* s_out = out + (size_t)B * K * T;    // [B][K][T]

    double* w64 = (double*)d_ws;               // 100.66 MB panel buffer (fits: proven R2-R6)

    conv_kernel<<<(B / 64) * (T / CBT), 256, 0, stream>>>(x, w0, w1, w2, u_out, w64);
    scan_kernel<<<B, 64, 0, stream>>>(w64, s_out);
}